// Round 7
// baseline (505.744 us; speedup 1.0000x reference)
//
#include <hip/hip_runtime.h>

#define T_STEPS 512
#define IN_DIM 11
#define H_DIM 16
#define ROW_F (T_STEPS * IN_DIM)    // 5632 floats per batch row
#define LOG2E 1.44269504088896340736f

typedef float v2f __attribute__((ext_vector_type(2)));
typedef float v4f __attribute__((ext_vector_type(4)));

// Packed fp32 FMA (v_pk_fma_f32): 2 MACs/instr, full rate.
__device__ __forceinline__ v2f pk_fma(v2f a, v2f b, v2f c) {
    v2f d;
    asm("v_pk_fma_f32 %0, %1, %2, %3" : "=v"(d) : "v"(a), "v"(b), "v"(c));
    return d;
}

// DPP quad_perm broadcast within each group of 4 lanes (VALU pipe).
template<int CTRL>
__device__ __forceinline__ float qperm(float v) {
    return __builtin_bit_cast(float,
        __builtin_amdgcn_update_dpp(0, __builtin_bit_cast(int, v),
                                    CTRL, 0xf, 0xf, true));
}

__device__ __forceinline__ float bcast_lane(float v, int l) {
    return __builtin_bit_cast(float,
        __builtin_amdgcn_readlane(__builtin_bit_cast(int, v), l));
}

// LSTM activation step: gsum -> gate act -> quad gate bcast -> cell -> h out.
#define ACT_STEP(gsum, cst, hv_out)                                           \
    {                                                                         \
        const float a_ = __builtin_fmaf(vAa,                                  \
            __builtin_amdgcn_rcpf(1.0f + __builtin_amdgcn_exp2f(gsum)), vBc); \
        const float gi_ = qperm<0x00>(a_);                                    \
        const float gf_ = qperm<0x55>(a_);                                    \
        const float gg_ = qperm<0xAA>(a_);                                    \
        const float go_ = qperm<0xFF>(a_);                                    \
        cst = __builtin_fmaf(gf_, cst, gi_ * gg_);                            \
        const float tc_ = __builtin_fmaf(2.0f,                                \
            __builtin_amdgcn_rcpf(1.0f +                                      \
                __builtin_amdgcn_exp2f(-2.0f * LOG2E * cst)), -1.0f);         \
        hv_out = go_ * tc_;                                                   \
    }

// FUSED 2-layer LSTM, one wave per batch. ROUND-6 POST-MORTEM: across
// R1/R5/R6, time tracks TOTAL ISSUED INSTRUCTIONS per step (R1 fewest ->
// 390us best; R6 cut LDS 15->5 but added VALU -> 411us). So: cut
// instructions. x[t] is WAVE-UNIFORM (one batch per wave) -> read x
// directly from global with uniform addresses; compiler turns these into
// s_load on the SCALAR pipe (0 VALU/LDS slots). Deletes: x LDS staging
// (3 glb loads + 3 LDS writes/chunk), 6 LDS x-reads/step, xlds buffers,
// chunk loop. h broadcast keeps the R1 slab write + ds_read_b128 pattern.
// Lane = 4*r + gate (i,f,g,o quads); weights M-scaled in pinned VGPRs.
__global__ __launch_bounds__(256, 4) void lstm2_head(
    const float* __restrict__ x,
    const float* __restrict__ Wih1, const float* __restrict__ Whh1,
    const float* __restrict__ bih1, const float* __restrict__ bhh1,
    const float* __restrict__ Wih2, const float* __restrict__ Whh2,
    const float* __restrict__ bih2, const float* __restrict__ bhh2,
    const float* __restrict__ Wd1, const float* __restrict__ bd1,
    const float* __restrict__ Wd2, const float* __restrict__ bd2,
    const float* __restrict__ Wd3, const float* __restrict__ bd3,
    float* __restrict__ out)
{
    __shared__ alignas(16) float shh[4][2][H_DIM];   // [wave][layer][r] h slabs

    const int lane = threadIdx.x & 63;
    const int wid = __builtin_amdgcn_readfirstlane((int)(threadIdx.x >> 6));
    const int b = blockIdx.x * 4 + wid;

    const int r   = lane >> 2;          // hidden index 0..15
    const int gt  = lane & 3;           // 0:i 1:f 2:g(tanh) 3:o
    const int row = gt * H_DIM + r;     // row in packed 4H weights

    const bool is_t = (gt == 2);
    const float M   = is_t ? (-2.0f * LOG2E) : (-LOG2E);
    const float vAa = is_t ? 2.0f : 1.0f;
    const float vBc = is_t ? -1.0f : 0.0f;

    // ---- per-lane weights (M-scaled), pinned ----
    float wx[IN_DIM];                   // layer-1 input weights (scalar x-dot)
    #pragma unroll
    for (int k = 0; k < IN_DIM; ++k) wx[k] = M * Wih1[row * IN_DIM + k];
    v2f wh1p[8], wi2p[8], wh2p[8];
    #pragma unroll
    for (int j = 0; j < 8; ++j) {
        wh1p[j] = (v2f){M * Whh1[row * H_DIM + 2 * j], M * Whh1[row * H_DIM + 2 * j + 1]};
        wi2p[j] = (v2f){M * Wih2[row * H_DIM + 2 * j], M * Wih2[row * H_DIM + 2 * j + 1]};
        wh2p[j] = (v2f){M * Whh2[row * H_DIM + 2 * j], M * Whh2[row * H_DIM + 2 * j + 1]};
    }
    const float bb1 = M * (bih1[row] + bhh1[row]);
    const float bb2 = M * (bih2[row] + bhh2[row]);
    #pragma unroll
    for (int k = 0; k < IN_DIM; ++k) asm volatile("" : "+v"(wx[k]));
    #pragma unroll
    for (int j = 0; j < 8; ++j) {
        asm volatile("" : "+v"(wh1p[j]));
        asm volatile("" : "+v"(wi2p[j]));
        asm volatile("" : "+v"(wh2p[j]));
    }

    float* const hs1 = &shh[wid][0][0];
    float* const hs2 = &shh[wid][1][0];
    const v4f* const h1q4 = (const v4f*)hs1;
    const v4f* const h2q4 = (const v4f*)hs2;
    hs1[r] = 0.0f;                      // same-wave init, no barrier needed
    hs2[r] = 0.0f;

    const float* __restrict__ xb = x + (size_t)b * ROW_F;   // wave-uniform base

    float c1 = 0.f, c2 = 0.f, h2v = 0.f, ssum = 0.f;
    v2f h1r[8], h2r[8];                 // register-resident h pairs
    #pragma unroll
    for (int j = 0; j < 8; ++j) { h1r[j] = (v2f){0.f, 0.f}; h2r[j] = (v2f){0.f, 0.f}; }

    #pragma unroll 8
    for (int t = 0; t < T_STEPS; ++t) {
        const float* __restrict__ xr = xb + t * IN_DIM;     // uniform addr -> s_load

        // ---- layer-1 x-dot (scalar pipe operands), two chains, bias folded ----
        float xs0 = __builtin_fmaf(wx[0], xr[0], bb1);
        float xs1 = wx[1] * xr[1];
        xs0 = __builtin_fmaf(wx[2], xr[2], xs0);
        xs1 = __builtin_fmaf(wx[3], xr[3], xs1);
        xs0 = __builtin_fmaf(wx[4], xr[4], xs0);
        xs1 = __builtin_fmaf(wx[5], xr[5], xs1);
        xs0 = __builtin_fmaf(wx[6], xr[6], xs0);
        xs1 = __builtin_fmaf(wx[7], xr[7], xs1);
        xs0 = __builtin_fmaf(wx[8], xr[8], xs0);
        xs1 = __builtin_fmaf(wx[9], xr[9], xs1);
        xs0 = __builtin_fmaf(wx[10], xr[10], xs0);

        // ---- layer-2 recurrent dot (h2r from prev step), two chains ----
        v2f a2p = pk_fma(wh2p[0], h2r[0], (v2f){bb2, 0.f});
        v2f a2q = pk_fma(wh2p[1], h2r[1], (v2f){0.f, 0.f});
        #pragma unroll
        for (int j = 2; j < 8; j += 2) {
            a2p = pk_fma(wh2p[j],     h2r[j],     a2p);
            a2q = pk_fma(wh2p[j + 1], h2r[j + 1], a2q);
        }

        // ---- layer-1 recurrent dot, x-dot folded into accumulator init ----
        v2f a1p = pk_fma(wh1p[0], h1r[0], (v2f){xs0, xs1});
        v2f a1q = pk_fma(wh1p[1], h1r[1], (v2f){0.f, 0.f});
        #pragma unroll
        for (int j = 2; j < 8; j += 2) {
            a1p = pk_fma(wh1p[j],     h1r[j],     a1p);
            a1q = pk_fma(wh1p[j + 1], h1r[j + 1], a1q);
        }

        const v2f s1 = a1p + a1q;
        const float g1 = s1.x + s1.y;
        float h1v;
        ACT_STEP(g1, c1, h1v);
        hs1[r] = h1v;                               // quad-replicated write
        // read fresh h1 ONCE (4x ds_read_b128): wi2 now, wh1 next step
        #pragma unroll
        for (int j = 0; j < 4; ++j) {
            const v4f q = h1q4[j];
            h1r[2 * j]     = (v2f){q.x, q.y};
            h1r[2 * j + 1] = (v2f){q.z, q.w};
        }

        #pragma unroll
        for (int j = 0; j < 8; j += 2) {
            a2p = pk_fma(wi2p[j],     h1r[j],     a2p);
            a2q = pk_fma(wi2p[j + 1], h1r[j + 1], a2q);
        }

        const v2f s2 = a2p + a2q;
        const float g2 = s2.x + s2.y;
        ACT_STEP(g2, c2, h2v);
        hs2[r] = h2v;
        #pragma unroll
        for (int j = 0; j < 4; ++j) {
            const v4f q = h2q4[j];
            h2r[2 * j]     = (v2f){q.x, q.y};
            h2r[2 * j + 1] = (v2f){q.z, q.w};
        }

        ssum += __builtin_amdgcn_exp2f(LOG2E * h2v);
    }

    // s[b,k] = exp(h2[T-1,k]) / sum_t exp(h2[t,k]); h2v replicated per quad.
    const float sv = __builtin_amdgcn_exp2f(LOG2E * h2v) / ssum;

    float ssb[H_DIM];
    #pragma unroll
    for (int k = 0; k < H_DIM; ++k) ssb[k] = bcast_lane(sv, 4 * k);

    // Dense head 16 -> 8 -> 8 -> 3 + softmax (one-time epilogue).
    const int r8 = lane & 7;
    float acc1 = bd1[r8];
    #pragma unroll
    for (int k = 0; k < H_DIM; ++k)
        acc1 = __builtin_fmaf(Wd1[r8 * H_DIM + k], ssb[k], acc1);

    float d1s[8];
    #pragma unroll
    for (int j = 0; j < 8; ++j) d1s[j] = bcast_lane(acc1, j);

    float acc2 = bd2[r8];
    #pragma unroll
    for (int k = 0; k < 8; ++k)
        acc2 = __builtin_fmaf(Wd2[r8 * 8 + k], d1s[k], acc2);

    float d2s[8];
    #pragma unroll
    for (int j = 0; j < 8; ++j) d2s[j] = bcast_lane(acc2, j);

    float lg = 0.f;
    if (lane < 3) {
        lg = bd3[lane];
        #pragma unroll
        for (int k = 0; k < 8; ++k)
            lg = __builtin_fmaf(Wd3[lane * 8 + k], d2s[k], lg);
    }
    const float l0 = bcast_lane(lg, 0);
    const float l1 = bcast_lane(lg, 1);
    const float l2 = bcast_lane(lg, 2);
    const float mx = fmaxf(l0, fmaxf(l1, l2));
    const float e0 = __builtin_amdgcn_exp2f(LOG2E * (l0 - mx));
    const float e1 = __builtin_amdgcn_exp2f(LOG2E * (l1 - mx));
    const float e2 = __builtin_amdgcn_exp2f(LOG2E * (l2 - mx));
    const float inv = 1.0f / (e0 + e1 + e2);
    if (lane < 3) {
        const float ev = (lane == 0) ? e0 : ((lane == 1) ? e1 : e2);
        out[b * 3 + lane] = ev * inv;
    }
}

extern "C" void kernel_launch(void* const* d_in, const int* in_sizes, int n_in,
                              void* d_out, int out_size, void* d_ws, size_t ws_size,
                              hipStream_t stream) {
    (void)in_sizes; (void)n_in; (void)out_size; (void)d_ws; (void)ws_size;
    const float* x    = (const float*)d_in[0];
    const float* Wih1 = (const float*)d_in[1];
    const float* Whh1 = (const float*)d_in[2];
    const float* bih1 = (const float*)d_in[3];
    const float* bhh1 = (const float*)d_in[4];
    const float* Wih2 = (const float*)d_in[5];
    const float* Whh2 = (const float*)d_in[6];
    const float* bih2 = (const float*)d_in[7];
    const float* bhh2 = (const float*)d_in[8];
    const float* Wd1  = (const float*)d_in[9];
    const float* bd1  = (const float*)d_in[10];
    const float* Wd2  = (const float*)d_in[11];
    const float* bd2  = (const float*)d_in[12];
    const float* Wd3  = (const float*)d_in[13];
    const float* bd3  = (const float*)d_in[14];

    lstm2_head<<<dim3(4096 / 4), dim3(256), 0, stream>>>(
        x, Wih1, Whh1, bih1, bhh1, Wih2, Whh2, bih2, bhh2,
        Wd1, bd1, Wd2, bd2, Wd3, bd3, (float*)d_out);
}